// Round 7
// baseline (75.454 us; speedup 1.0000x reference)
//
#include <hip/hip_runtime.h>
#include <hip/hip_bf16.h>

// GTAT integrated: B=8,N=4096,D=256,TD=64,GD=73,L=2 -> 32768 rows, row-parallel.
// TA (t,Tp,p,q) -> TB (beta,T_out,M=T_out@Wo swz, r',u,c, W swizzles)
//  -> fused (all 4 GEMM stages, h in registers)
// R7: 32 rows/WG x 1024 WGs (was 64x512): per-thread state halves (h16+acc16),
//     fits the 64-VGPR budget the allocator insists on -> no scratch spills;
//     4 WG/CU (LDS ~33KB) -> ~32 waves/CU latency hiding; alpha-gen VALU halves.

typedef float f32x4 __attribute__((ext_vector_type(4)));
typedef short bf16x8 __attribute__((ext_vector_type(8)));

__device__ __forceinline__ unsigned short f2bf(float f) {
  unsigned int u = __builtin_bit_cast(unsigned int, f);
  u += 0x7FFFu + ((u >> 16) & 1u);   // round-to-nearest-even
  return (unsigned short)(u >> 16);
}
__device__ __forceinline__ float bf2f(unsigned short u) {
  return __builtin_bit_cast(float, (unsigned int)u << 16);
}
__device__ __forceinline__ float lrelu(float x) { return x > 0.f ? x : 0.01f * x; }

// ---- DPP 16-lane reduction (VALU only, no LDS pipe) ----
template <int CTRL>
__device__ __forceinline__ float dpp_ror_add(float v) {
  int s = __builtin_amdgcn_update_dpp(0, __builtin_bit_cast(int, v), CTRL, 0xf, 0xf, true);
  return v + __builtin_bit_cast(float, s);
}
__device__ __forceinline__ float sum16(float v) {   // all 16 lanes of each row get the sum
  v = dpp_ror_add<0x128>(v);  // row_ror:8
  v = dpp_ror_add<0x124>(v);  // row_ror:4
  v = dpp_ror_add<0x122>(v);  // row_ror:2
  v = dpp_ror_add<0x121>(v);  // row_ror:1
  return v;
}

// ---- block reduce helpers (256 threads, all must call) ----
__device__ __forceinline__ float block_sum(float v, float* s4, int t) {
  v = sum16(v);
  v += __shfl_xor(v, 16, 64);
  v += __shfl_xor(v, 32, 64);
  __syncthreads();
  if ((t & 63) == 0) s4[t >> 6] = v;
  __syncthreads();
  return s4[0] + s4[1] + s4[2] + s4[3];
}
__device__ __forceinline__ float block_max(float v, float* s4, int t) {
#pragma unroll
  for (int m = 1; m < 64; m <<= 1) v = fmaxf(v, __shfl_xor(v, m, 64));
  __syncthreads();
  if ((t & 63) == 0) s4[t >> 6] = v;
  __syncthreads();
  return fmaxf(fmaxf(s4[0], s4[1]), fmaxf(s4[2], s4[3]));
}

// B-operand swizzled layout: elem(k,n) -> ((((k>>5)*16 + (n>>4))*4 + ((k>>3)&3))*16 + (n&15))*8 + (k&7)
__device__ __forceinline__ int swz_off(int k, int n) {
  return ((((k >> 5) * 16 + (n >> 4)) * 4 + ((k >> 3) & 3)) * 16 + (n & 15)) * 8 + (k & 7);
}
// A-frag LDS byte offset for (k=n, row m in [0,32)), XOR-swizzled
__device__ __forceinline__ int alds_byte(int n, int m) {
  int grp = n >> 3;
  int base = (grp * 32 + m) * 16 + (n & 7) * 2;
  return base ^ ((grp & 7) << 4);
}

// ============ TA: t rows -> Tp rows + p,q  (grid 512 = L*256, 256 thr) ============
__global__ void ta_kernel(const float* __restrict__ gdv,
                          const float* __restrict__ g1W, const float* __restrict__ g1b,
                          const float* __restrict__ g2W, const float* __restrict__ g2b,
                          const float* __restrict__ grW, const float* __restrict__ grb,
                          const float* __restrict__ Wt, const float* __restrict__ bt,
                          const float* __restrict__ wat,
                          float* __restrict__ Tp, float* __restrict__ pb, float* __restrict__ qb) {
  int l = blockIdx.x >> 8, i = blockIdx.x & 255, t = threadIdx.x;
  __shared__ float gs[73], as_[64], ts[64], s4[4];
  float gv = (t < 73) ? gdv[i * 73 + t] : 0.f;
  float gsum = block_sum(gv, s4, t);
  if (t < 73) gs[t] = gv / (gsum + 1e-6f);
  __syncthreads();
  if (t < 64) {
    float a = g1b[t], gr = grb[t];
    for (int k = 0; k < 73; ++k) { float gk = gs[k]; a = fmaf(gk, g1W[k * 64 + t], a); gr = fmaf(gk, grW[k * 64 + t], gr); }
    as_[t] = fmaxf(a, 0.f);
    ts[t] = gr + g2b[t];
  }
  __syncthreads();
  float tv = 0.f;
  if (t < 64) {
    tv = ts[t];
    for (int k = 0; k < 64; ++k) tv = fmaf(as_[k], g2W[k * 64 + t], tv);
  }
  __syncthreads();
  if (t < 64) ts[t] = tv;
  __syncthreads();
  float tp = bt[l * 256 + t];
  for (int k = 0; k < 64; ++k) tp = fmaf(ts[k], Wt[(l * 64 + k) * 256 + t], tp);
  Tp[(l * 256 + i) * 256 + t] = tp;
  float pp = block_sum(tp * wat[l * 512 + t], s4, t);
  float qq = block_sum(tp * wat[l * 512 + 256 + t], s4, t);
  if (t == 0) { pb[l * 256 + i] = pp; qb[l * 256 + i] = qq; }
}

// ====== TB: beta,T_out row -> M row (swz bf16), r', u, c ; + W_in/W_out swizzles ======
__global__ void tb_kernel(const int* __restrict__ adj, const float* __restrict__ Tp,
                          const float* __restrict__ pb, const float* __restrict__ qb,
                          const float* __restrict__ batopo, const float* __restrict__ Wo,
                          const float* __restrict__ wafeat, const float* __restrict__ bafeat,
                          const float* __restrict__ Wf, const float* __restrict__ bfv,
                          const float* __restrict__ Win, const float* __restrict__ Wout,
                          float* __restrict__ rp, float* __restrict__ ub, float* __restrict__ cb,
                          unsigned short* __restrict__ Uws) {
  int b = blockIdx.x, t = threadIdx.x;
  if (b >= 512) {                               // weight swizzle blocks
    int bb = b - 512;
    const float* src = (bb < 16) ? Win : Wout;
    unsigned short* dst = Uws + ((bb < 16) ? 0 : 65536);
    int r0 = (bb & 15) * 16;
    for (int kk = 0; kk < 16; ++kk) {
      int k = r0 + kk;
      dst[swz_off(k, t)] = f2bf(src[k * 256 + t]);
    }
    return;
  }
  int l = b >> 8, i = b & 255;
  __shared__ float beta[256], tout[256], s4[4];
  float e = pb[l * 256 + i] + qb[l * 256 + t] + batopo[l];
  e = lrelu(e);
  if (adj[i * 256 + t] == 0) e = -1e9f;
  float mx = block_max(e, s4, t);
  float w = __expf(e - mx);
  float Z = block_sum(w, s4, t);
  beta[t] = w / Z;
  __syncthreads();
  float acc = 0.f;
  for (int j = 0; j < 256; ++j) acc = fmaf(beta[j], Tp[(l * 256 + j) * 256 + t], acc);
  tout[t] = acc;
  __syncthreads();
  const float* WoL = Wo + l * 65536;
  float macc = 0.f;
  for (int h2 = 0; h2 < 256; ++h2) macc = fmaf(tout[h2], WoL[h2 * 256 + t], macc);
  Uws[131072 + l * 65536 + swz_off(i, t)] = f2bf(macc);   // M_l row i
  const float* wf = wafeat + l * 512;
  float rsum = block_sum(tout[t] * wf[256 + t], s4, t);
  if (t == 0) rp[l * 256 + i] = rsum + bafeat[l];
  float usum = block_sum(Wf[(l * 256 + i) * 256 + t] * wf[t], s4, t);
  if (t == 0) ub[l * 256 + i] = usum;
  if (i == 0) {
    float csum = block_sum(bfv[l * 256 + t] * wf[t], s4, t);
    if (t == 0) cb[l] = csum;
  }
}

// ============ fused kernel: 4 GEMM stages, 1024 WGs x 512 thr, 32 rows/WG ============
// wave tile = 32 rows x 32 cols (2x2 frags of 16x16x32). h in regs (16 f32/thread).
#define MFMA(A, B, C) __builtin_amdgcn_mfma_f32_16x16x32_bf16(A, B, C, 0, 0, 0)

__device__ __forceinline__ void kloop(const char* smc, const unsigned short* Bws,
                                      int wid, int lane, int li, int g, f32x4 acc[2][2]) {
  const bf16x8* Bw = (const bf16x8*)Bws + wid * 2 * 64 + lane;
  bf16x8 b0 = Bw[0], b1 = Bw[64];
#pragma unroll
  for (int kb = 0; kb < 8; ++kb) {
    bf16x8 nb0, nb1;
    if (kb < 7) {            // 1-deep B prefetch covers ~200cy L2 latency
      nb0 = Bw[(kb + 1) * 1024];
      nb1 = Bw[(kb + 1) * 1024 + 64];
    }
    int grp = kb * 4 + g;
    int ab = ((grp * 32 + li) * 16) ^ ((grp & 7) << 4);
    bf16x8 a0 = *(const bf16x8*)(smc + ab);
    bf16x8 a1 = *(const bf16x8*)(smc + ab + 256);
    acc[0][0] = MFMA(a0, b0, acc[0][0]);
    acc[1][0] = MFMA(a1, b0, acc[1][0]);
    acc[0][1] = MFMA(a0, b1, acc[0][1]);
    acc[1][1] = MFMA(a1, b1, acc[1][1]);
    if (kb < 7) { b0 = nb0; b1 = nb1; }
  }
}

// s = h . u + c per row (rows 0..31); red is [16][32] float
#define S_REDUCE(UBARR, CBV)                                                   \
  {                                                                            \
    float u0_ = UBARR[ncol[0]], u1_ = UBARR[ncol[1]];                          \
    _Pragma("unroll") for (int rt = 0; rt < 2; ++rt) {                         \
      float sp[4];                                                             \
      _Pragma("unroll") for (int r = 0; r < 4; ++r)                            \
        sp[r] = h[rt][0][r] * u0_ + h[rt][1][r] * u1_;                         \
      _Pragma("unroll") for (int r = 0; r < 4; ++r) sp[r] = sum16(sp[r]);      \
      if (li == 0) {                                                           \
        _Pragma("unroll") for (int r = 0; r < 4; ++r)                          \
          red[wid][rt * 16 + g * 4 + r] = sp[r];                               \
      }                                                                        \
    }                                                                          \
    __syncthreads();                                                           \
    if (t < 32) {                                                              \
      float S = 0.f;                                                           \
      _Pragma("unroll") for (int w = 0; w < 8; ++w) S += red[w][t];            \
      row_s[t] = S + (CBV);                                                    \
    }                                                                          \
    __syncthreads();                                                           \
  }

// LN stats (sum -> red[wid], sumsq -> red[8+wid])
#define LN_STATS()                                                             \
  {                                                                            \
    _Pragma("unroll") for (int rt = 0; rt < 2; ++rt) {                         \
      float sA[4], sQ[4];                                                      \
      _Pragma("unroll") for (int r = 0; r < 4; ++r) {                          \
        float a0 = h[rt][0][r], a1 = h[rt][1][r];                              \
        sA[r] = a0 + a1;                                                       \
        sQ[r] = a0 * a0 + a1 * a1;                                             \
      }                                                                        \
      _Pragma("unroll") for (int r = 0; r < 4; ++r) {                          \
        sA[r] = sum16(sA[r]); sQ[r] = sum16(sQ[r]);                            \
      }                                                                        \
      if (li == 0) {                                                           \
        _Pragma("unroll") for (int r = 0; r < 4; ++r) {                        \
          int row_ = rt * 16 + g * 4 + r;                                      \
          red[wid][row_] = sA[r]; red[8 + wid][row_] = sQ[r];                  \
        }                                                                      \
      }                                                                        \
    }                                                                          \
    __syncthreads();                                                           \
    if (t < 32) {                                                              \
      float S = 0.f, Q = 0.f;                                                  \
      _Pragma("unroll") for (int w = 0; w < 8; ++w) { S += red[w][t]; Q += red[8 + w][t]; } \
      float mean_ = S * (1.f / 256.f);                                         \
      float var_ = Q * (1.f / 256.f) - mean_ * mean_;                          \
      mr_s[t][0] = mean_; mr_s[t][1] = rsqrtf(var_ + 1e-5f);                   \
    }                                                                          \
    __syncthreads();                                                           \
  }

__global__ __launch_bounds__(512) void fused_kernel(
    const float* __restrict__ x,
    const float* __restrict__ rp, const float* __restrict__ ub, const float* __restrict__ cbp,
    const unsigned short* __restrict__ Uws,
    const float* __restrict__ bin, const float* __restrict__ bo,
    const float* __restrict__ lng, const float* __restrict__ lnb,
    const float* __restrict__ bout, const float* __restrict__ lngf, const float* __restrict__ lnbf,
    float* __restrict__ out) {
  __shared__ unsigned short alds[8192];      // 16KB A fragments (32 rows x 256)
  __shared__ float c_bin[256], c_bout[256], c_lngf[256], c_lnbf[256];
  __shared__ float c_ub[2][256], c_bo[2][256], c_lng[2][256], c_lnb[2][256], c_rp[2][256];
  __shared__ float red[16][32];
  __shared__ float row_s[32], invz_s[32];
  __shared__ float mr_s[32][2];
  __shared__ float scal_s[4];                // Rm0, Rm1, cb0, cb1
  char* smc = (char*)alds;

  const int wg = blockIdx.x, t = threadIdx.x;
  const int wid = t >> 6, lane = t & 63, li = lane & 15, g = lane >> 4;
  const int rowbase = wg * 32;
  int ncol[2]; ncol[0] = wid * 32 + li; ncol[1] = wid * 32 + 16 + li;

  // constants -> LDS
  if (t < 256) {
    c_bin[t] = bin[t]; c_ub[0][t] = ub[t]; c_bo[0][t] = bo[t];
    c_lng[0][t] = lng[t]; c_lnb[0][t] = lnb[t]; c_rp[0][t] = rp[t];
  } else {
    int u = t - 256;
    c_bout[u] = bout[u]; c_lngf[u] = lngf[u]; c_lnbf[u] = lnbf[u];
    c_ub[1][u] = ub[256 + u]; c_bo[1][u] = bo[256 + u];
    c_lng[1][u] = lng[256 + u]; c_lnb[1][u] = lnb[256 + u]; c_rp[1][u] = rp[256 + u];
  }
  if (t == 0) { scal_s[2] = cbp[0]; scal_s[3] = cbp[1]; }

  // stage x -> alds (bf16, A-frag layout); coalesced float4 global reads
#pragma unroll
  for (int it = 0; it < 4; ++it) {
    int flat = it * 2048 + t * 4;
    int m = flat >> 8, col = flat & 255;
    const float4 xv = *(const float4*)(x + (rowbase + m) * 256 + col);
    ushort4 pk; pk.x = f2bf(xv.x); pk.y = f2bf(xv.y); pk.z = f2bf(xv.z); pk.w = f2bf(xv.w);
    *(ushort4*)(smc + alds_byte(col, m)) = pk;
  }
  __syncthreads();
  if (wid < 2) {   // Rm_l = max_f r'_l (once, 2 waves)
    float m2 = fmaxf(fmaxf(c_rp[wid][lane], c_rp[wid][lane + 64]),
                     fmaxf(c_rp[wid][lane + 128], c_rp[wid][lane + 192]));
#pragma unroll
    for (int mm = 1; mm < 64; mm <<= 1) m2 = fmaxf(m2, __shfl_xor(m2, mm, 64));
    if (lane == 0) scal_s[wid] = m2;
  }

  float h[2][2][4];

  // ---- stage 0: h0 = x@Win + bin ; s0 ----
  {
    f32x4 acc[2][2];
#pragma unroll
    for (int a = 0; a < 2; ++a)
#pragma unroll
      for (int c = 0; c < 2; ++c) { f32x4 z = {0.f, 0.f, 0.f, 0.f}; acc[a][c] = z; }
    kloop(smc, Uws, wid, lane, li, g, acc);
#pragma unroll
    for (int rt = 0; rt < 2; ++rt)
#pragma unroll
      for (int ct = 0; ct < 2; ++ct)
#pragma unroll
        for (int r = 0; r < 4; ++r) h[rt][ct][r] = acc[rt][ct][r] + c_bin[ncol[ct]];
    S_REDUCE(c_ub[0], scal_s[2]);
  }

  // ---- layers ----
#pragma unroll 1
  for (int l = 0; l < 2; ++l) {
    // alpha (un-normalized bf16) -> alds via b128 writes; Z partials
    {
      int row = t & 31, p = t >> 5;       // 16 threads per row, 16 features each
      float sm = row_s[row];
      float mx = lrelu(sm + scal_s[l]);   // exact max: lrelu monotone
      float z = 0.f;
#pragma unroll
      for (int j = 0; j < 2; ++j) {
        int grp = p * 2 + j;
        float w0 = __expf(lrelu(sm + c_rp[l][grp * 8 + 0]) - mx);
        float w1 = __expf(lrelu(sm + c_rp[l][grp * 8 + 1]) - mx);
        float w2 = __expf(lrelu(sm + c_rp[l][grp * 8 + 2]) - mx);
        float w3 = __expf(lrelu(sm + c_rp[l][grp * 8 + 3]) - mx);
        float w4 = __expf(lrelu(sm + c_rp[l][grp * 8 + 4]) - mx);
        float w5 = __expf(lrelu(sm + c_rp[l][grp * 8 + 5]) - mx);
        float w6 = __expf(lrelu(sm + c_rp[l][grp * 8 + 6]) - mx);
        float w7 = __expf(lrelu(sm + c_rp[l][grp * 8 + 7]) - mx);
        unsigned short u0 = f2bf(w0), u1 = f2bf(w1), u2 = f2bf(w2), u3 = f2bf(w3);
        unsigned short u4 = f2bf(w4), u5 = f2bf(w5), u6 = f2bf(w6), u7 = f2bf(w7);
        z += bf2f(u0) + bf2f(u1) + bf2f(u2) + bf2f(u3) +
             bf2f(u4) + bf2f(u5) + bf2f(u6) + bf2f(u7);
        uint4 pk;
        pk.x = (unsigned int)u0 | ((unsigned int)u1 << 16);
        pk.y = (unsigned int)u2 | ((unsigned int)u3 << 16);
        pk.z = (unsigned int)u4 | ((unsigned int)u5 << 16);
        pk.w = (unsigned int)u6 | ((unsigned int)u7 << 16);
        int byte = ((grp * 32 + row) * 16) ^ ((grp & 7) << 4);
        *(uint4*)(smc + byte) = pk;
      }
      red[p][row] = z;
    }
    __syncthreads();
    if (t < 32) {
      float Z = 0.f;
#pragma unroll
      for (int p = 0; p < 16; ++p) Z += red[p][t];
      invz_s[t] = 1.f / Z;
    }
    __syncthreads();

    f32x4 acc[2][2];
#pragma unroll
    for (int a = 0; a < 2; ++a)
#pragma unroll
      for (int c = 0; c < 2; ++c) { f32x4 z = {0.f, 0.f, 0.f, 0.f}; acc[a][c] = z; }
    kloop(smc, Uws + 131072 + l * 65536, wid, lane, li, g, acc);

    // h = LN(acc/Z + bo + h)
#pragma unroll
    for (int rt = 0; rt < 2; ++rt)
#pragma unroll
      for (int r = 0; r < 4; ++r) {
        int row = rt * 16 + g * 4 + r;
        float iz = invz_s[row];
#pragma unroll
        for (int ct = 0; ct < 2; ++ct)
          h[rt][ct][r] = fmaf(acc[rt][ct][r], iz, c_bo[l][ncol[ct]] + h[rt][ct][r]);
      }
    LN_STATS();
#pragma unroll
    for (int rt = 0; rt < 2; ++rt)
#pragma unroll
      for (int r = 0; r < 4; ++r) {
        int row = rt * 16 + g * 4 + r;
        float mean = mr_s[row][0], rstd = mr_s[row][1];
#pragma unroll
        for (int ct = 0; ct < 2; ++ct)
          h[rt][ct][r] = (h[rt][ct][r] - mean) * rstd * c_lng[l][ncol[ct]] + c_lnb[l][ncol[ct]];
      }
    if (l == 0) S_REDUCE(c_ub[1], scal_s[3]);
  }

  // ---- stage 3: out = LN(h@Wout + bout) ----
#pragma unroll
  for (int rt = 0; rt < 2; ++rt)
#pragma unroll
    for (int ct = 0; ct < 2; ++ct)
#pragma unroll
      for (int r = 0; r < 4; ++r) {
        int row = rt * 16 + g * 4 + r;
        *(unsigned short*)(smc + alds_byte(ncol[ct], row)) = f2bf(h[rt][ct][r]);
      }
  __syncthreads();
  {
    f32x4 acc[2][2];
#pragma unroll
    for (int a = 0; a < 2; ++a)
#pragma unroll
      for (int c = 0; c < 2; ++c) { f32x4 z = {0.f, 0.f, 0.f, 0.f}; acc[a][c] = z; }
    kloop(smc, Uws + 65536, wid, lane, li, g, acc);
#pragma unroll
    for (int rt = 0; rt < 2; ++rt)
#pragma unroll
      for (int ct = 0; ct < 2; ++ct)
#pragma unroll
        for (int r = 0; r < 4; ++r) h[rt][ct][r] = acc[rt][ct][r] + c_bout[ncol[ct]];
    LN_STATS();
#pragma unroll
    for (int rt = 0; rt < 2; ++rt)
#pragma unroll
      for (int r = 0; r < 4; ++r) {
        int row = rt * 16 + g * 4 + r;
        float mean = mr_s[row][0], rstd = mr_s[row][1];
#pragma unroll
        for (int ct = 0; ct < 2; ++ct)
          out[(rowbase + row) * 256 + ncol[ct]] =
              (h[rt][ct][r] - mean) * rstd * c_lngf[ncol[ct]] + c_lnbf[ncol[ct]];
      }
  }
}

extern "C" void kernel_launch(void* const* d_in, const int* in_sizes, int n_in,
                              void* d_out, int out_size, void* d_ws, size_t ws_size,
                              hipStream_t stream) {
  const float* x    = (const float*)d_in[0];
  const int*   adj  = (const int*)d_in[1];
  const float* gdv  = (const float*)d_in[2];
  const float* Win  = (const float*)d_in[3];
  const float* bin  = (const float*)d_in[4];
  const float* Wout = (const float*)d_in[5];
  const float* bout = (const float*)d_in[6];
  const float* g1W  = (const float*)d_in[7];
  const float* g1b  = (const float*)d_in[8];
  const float* g2W  = (const float*)d_in[9];
  const float* g2b  = (const float*)d_in[10];
  const float* grW  = (const float*)d_in[11];
  const float* grb  = (const float*)d_in[12];
  const float* lngf = (const float*)d_in[13];
  const float* lnbf = (const float*)d_in[14];
  const float* Wf   = (const float*)d_in[15];
  const float* bfv  = (const float*)d_in[16];
  const float* Wt   = (const float*)d_in[17];
  const float* bt   = (const float*)d_in[18];
  const float* waf  = (const float*)d_in[19];
  const float* baf  = (const float*)d_in[20];
  const float* wat  = (const float*)d_in[21];
  const float* bat  = (const float*)d_in[22];
  const float* Wo   = (const float*)d_in[23];
  const float* bo   = (const float*)d_in[24];
  const float* lng  = (const float*)d_in[25];
  const float* lnb  = (const float*)d_in[26];
  float* out = (float*)d_out;

  float* W = (float*)d_ws;
  float* Tp = W;                                 // 2*256*256
  float* pb = W + 131072;                        // 512
  float* qb = W + 131584;
  float* rp = W + 132096;
  float* ub = W + 132608;
  float* cb = W + 133120;                        // 2 (+pad)
  unsigned short* Uws = (unsigned short*)(W + 133184);  // Win|Wout|M0|M1 swz bf16 (512KB)

  ta_kernel<<<512, 256, 0, stream>>>(gdv, g1W, g1b, g2W, g2b, grW, grb, Wt, bt, wat, Tp, pb, qb);
  tb_kernel<<<544, 256, 0, stream>>>(adj, Tp, pb, qb, bat, Wo, waf, baf, Wf, bfv, Win, Wout, rp, ub, cb, Uws);
  fused_kernel<<<1024, 512, 0, stream>>>(x, rp, ub, cb, Uws, bin, bo, lng, lnb, bout, lngf, lnbf, out);
}

// Round 9
// 69.569 us; speedup vs baseline: 1.0846x; 1.0846x over previous
//
#include <hip/hip_runtime.h>
#include <hip/hip_bf16.h>

// GTAT integrated: B=8,N=4096,D=256,TD=64,GD=73,L=2 -> 32768 rows, row-parallel.
// TA (t,Tp,p,q) -> TB (beta,T_out,M=T_out@Wo swz, r',u,c, W swizzles)
//  -> fused (all 4 GEMM stages, h in registers, 32 rows/WG x 1024 WGs)
// R9: compile fix of R8 — nontemporal builtins need clang ext_vector, not HIP float4.
//     (phase-desync stagger, 2-deep B prefetch, setprio, NT x/out streams)

typedef float f32x4 __attribute__((ext_vector_type(4)));
typedef short bf16x8 __attribute__((ext_vector_type(8)));

__device__ __forceinline__ unsigned short f2bf(float f) {
  unsigned int u = __builtin_bit_cast(unsigned int, f);
  u += 0x7FFFu + ((u >> 16) & 1u);   // round-to-nearest-even
  return (unsigned short)(u >> 16);
}
__device__ __forceinline__ float bf2f(unsigned short u) {
  return __builtin_bit_cast(float, (unsigned int)u << 16);
}
__device__ __forceinline__ float lrelu(float x) { return x > 0.f ? x : 0.01f * x; }

// ---- DPP 16-lane reduction (VALU only, no LDS pipe) ----
template <int CTRL>
__device__ __forceinline__ float dpp_ror_add(float v) {
  int s = __builtin_amdgcn_update_dpp(0, __builtin_bit_cast(int, v), CTRL, 0xf, 0xf, true);
  return v + __builtin_bit_cast(float, s);
}
__device__ __forceinline__ float sum16(float v) {   // all 16 lanes of each row get the sum
  v = dpp_ror_add<0x128>(v);  // row_ror:8
  v = dpp_ror_add<0x124>(v);  // row_ror:4
  v = dpp_ror_add<0x122>(v);  // row_ror:2
  v = dpp_ror_add<0x121>(v);  // row_ror:1
  return v;
}

// ---- block reduce helpers (256 threads, all must call) ----
__device__ __forceinline__ float block_sum(float v, float* s4, int t) {
  v = sum16(v);
  v += __shfl_xor(v, 16, 64);
  v += __shfl_xor(v, 32, 64);
  __syncthreads();
  if ((t & 63) == 0) s4[t >> 6] = v;
  __syncthreads();
  return s4[0] + s4[1] + s4[2] + s4[3];
}
__device__ __forceinline__ float block_max(float v, float* s4, int t) {
#pragma unroll
  for (int m = 1; m < 64; m <<= 1) v = fmaxf(v, __shfl_xor(v, m, 64));
  __syncthreads();
  if ((t & 63) == 0) s4[t >> 6] = v;
  __syncthreads();
  return fmaxf(fmaxf(s4[0], s4[1]), fmaxf(s4[2], s4[3]));
}

// B-operand swizzled layout: elem(k,n) -> ((((k>>5)*16 + (n>>4))*4 + ((k>>3)&3))*16 + (n&15))*8 + (k&7)
__device__ __forceinline__ int swz_off(int k, int n) {
  return ((((k >> 5) * 16 + (n >> 4)) * 4 + ((k >> 3) & 3)) * 16 + (n & 15)) * 8 + (k & 7);
}
// A-frag LDS byte offset for (k=n, row m in [0,32)), XOR-swizzled
__device__ __forceinline__ int alds_byte(int n, int m) {
  int grp = n >> 3;
  int base = (grp * 32 + m) * 16 + (n & 7) * 2;
  return base ^ ((grp & 7) << 4);
}

// ============ TA: t rows -> Tp rows + p,q  (grid 512 = L*256, 256 thr) ============
__global__ void ta_kernel(const float* __restrict__ gdv,
                          const float* __restrict__ g1W, const float* __restrict__ g1b,
                          const float* __restrict__ g2W, const float* __restrict__ g2b,
                          const float* __restrict__ grW, const float* __restrict__ grb,
                          const float* __restrict__ Wt, const float* __restrict__ bt,
                          const float* __restrict__ wat,
                          float* __restrict__ Tp, float* __restrict__ pb, float* __restrict__ qb) {
  int l = blockIdx.x >> 8, i = blockIdx.x & 255, t = threadIdx.x;
  __shared__ float gs[73], as_[64], ts[64], s4[4];
  float gv = (t < 73) ? gdv[i * 73 + t] : 0.f;
  float gsum = block_sum(gv, s4, t);
  if (t < 73) gs[t] = gv / (gsum + 1e-6f);
  __syncthreads();
  if (t < 64) {
    float a = g1b[t], gr = grb[t];
    for (int k = 0; k < 73; ++k) { float gk = gs[k]; a = fmaf(gk, g1W[k * 64 + t], a); gr = fmaf(gk, grW[k * 64 + t], gr); }
    as_[t] = fmaxf(a, 0.f);
    ts[t] = gr + g2b[t];
  }
  __syncthreads();
  float tv = 0.f;
  if (t < 64) {
    tv = ts[t];
    for (int k = 0; k < 64; ++k) tv = fmaf(as_[k], g2W[k * 64 + t], tv);
  }
  __syncthreads();
  if (t < 64) ts[t] = tv;
  __syncthreads();
  float tp = bt[l * 256 + t];
  for (int k = 0; k < 64; ++k) tp = fmaf(ts[k], Wt[(l * 64 + k) * 256 + t], tp);
  Tp[(l * 256 + i) * 256 + t] = tp;
  float pp = block_sum(tp * wat[l * 512 + t], s4, t);
  float qq = block_sum(tp * wat[l * 512 + 256 + t], s4, t);
  if (t == 0) { pb[l * 256 + i] = pp; qb[l * 256 + i] = qq; }
}

// ====== TB: beta,T_out row -> M row (swz bf16), r', u, c ; + W_in/W_out swizzles ======
__global__ void tb_kernel(const int* __restrict__ adj, const float* __restrict__ Tp,
                          const float* __restrict__ pb, const float* __restrict__ qb,
                          const float* __restrict__ batopo, const float* __restrict__ Wo,
                          const float* __restrict__ wafeat, const float* __restrict__ bafeat,
                          const float* __restrict__ Wf, const float* __restrict__ bfv,
                          const float* __restrict__ Win, const float* __restrict__ Wout,
                          float* __restrict__ rp, float* __restrict__ ub, float* __restrict__ cb,
                          unsigned short* __restrict__ Uws) {
  int b = blockIdx.x, t = threadIdx.x;
  if (b >= 512) {                               // weight swizzle blocks
    int bb = b - 512;
    const float* src = (bb < 16) ? Win : Wout;
    unsigned short* dst = Uws + ((bb < 16) ? 0 : 65536);
    int r0 = (bb & 15) * 16;
    for (int kk = 0; kk < 16; ++kk) {
      int k = r0 + kk;
      dst[swz_off(k, t)] = f2bf(src[k * 256 + t]);
    }
    return;
  }
  int l = b >> 8, i = b & 255;
  __shared__ float beta[256], tout[256], s4[4];
  float e = pb[l * 256 + i] + qb[l * 256 + t] + batopo[l];
  e = lrelu(e);
  if (adj[i * 256 + t] == 0) e = -1e9f;
  float mx = block_max(e, s4, t);
  float w = __expf(e - mx);
  float Z = block_sum(w, s4, t);
  beta[t] = w / Z;
  __syncthreads();
  float acc = 0.f;
  for (int j = 0; j < 256; ++j) acc = fmaf(beta[j], Tp[(l * 256 + j) * 256 + t], acc);
  tout[t] = acc;
  __syncthreads();
  const float* WoL = Wo + l * 65536;
  float macc = 0.f;
  for (int h2 = 0; h2 < 256; ++h2) macc = fmaf(tout[h2], WoL[h2 * 256 + t], macc);
  Uws[131072 + l * 65536 + swz_off(i, t)] = f2bf(macc);   // M_l row i
  const float* wf = wafeat + l * 512;
  float rsum = block_sum(tout[t] * wf[256 + t], s4, t);
  if (t == 0) rp[l * 256 + i] = rsum + bafeat[l];
  float usum = block_sum(Wf[(l * 256 + i) * 256 + t] * wf[t], s4, t);
  if (t == 0) ub[l * 256 + i] = usum;
  if (i == 0) {
    float csum = block_sum(bfv[l * 256 + t] * wf[t], s4, t);
    if (t == 0) cb[l] = csum;
  }
}

// ============ fused kernel: 4 GEMM stages, 1024 WGs x 512 thr, 32 rows/WG ============
// wave tile = 32 rows x 32 cols (2x2 frags of 16x16x32). h in regs (16 f32/thread).
#define MFMA(A, B, C) __builtin_amdgcn_mfma_f32_16x16x32_bf16(A, B, C, 0, 0, 0)

__device__ __forceinline__ void kloop(const char* smc, const unsigned short* Bws,
                                      int wid, int lane, int li, int g, f32x4 acc[2][2]) {
  const bf16x8* Bw = (const bf16x8*)Bws + wid * 2 * 64 + lane;
  // 2-deep B pipeline: hold kb and kb+1, issue kb+2 while MFMAing kb
  bf16x8 b0a = Bw[0], b1a = Bw[64];
  bf16x8 b0b = Bw[1024], b1b = Bw[1024 + 64];
#pragma unroll
  for (int kb = 0; kb < 8; ++kb) {
    bf16x8 nb0, nb1;
    if (kb < 6) {
      nb0 = Bw[(kb + 2) * 1024];
      nb1 = Bw[(kb + 2) * 1024 + 64];
    }
    int grp = kb * 4 + g;
    int ab = ((grp * 32 + li) * 16) ^ ((grp & 7) << 4);
    bf16x8 a0 = *(const bf16x8*)(smc + ab);
    bf16x8 a1 = *(const bf16x8*)(smc + ab + 256);
    __builtin_amdgcn_s_setprio(1);
    acc[0][0] = MFMA(a0, b0a, acc[0][0]);
    acc[1][0] = MFMA(a1, b0a, acc[1][0]);
    acc[0][1] = MFMA(a0, b1a, acc[0][1]);
    acc[1][1] = MFMA(a1, b1a, acc[1][1]);
    __builtin_amdgcn_s_setprio(0);
    b0a = b0b; b1a = b1b;
    if (kb < 6) { b0b = nb0; b1b = nb1; }
  }
}

// s = h . u + c per row (rows 0..31); red is [16][32] float
#define S_REDUCE(UBARR, CBV)                                                   \
  {                                                                            \
    float u0_ = UBARR[ncol[0]], u1_ = UBARR[ncol[1]];                          \
    _Pragma("unroll") for (int rt = 0; rt < 2; ++rt) {                         \
      float sp[4];                                                             \
      _Pragma("unroll") for (int r = 0; r < 4; ++r)                            \
        sp[r] = h[rt][0][r] * u0_ + h[rt][1][r] * u1_;                         \
      _Pragma("unroll") for (int r = 0; r < 4; ++r) sp[r] = sum16(sp[r]);      \
      if (li == 0) {                                                           \
        _Pragma("unroll") for (int r = 0; r < 4; ++r)                          \
          red[wid][rt * 16 + g * 4 + r] = sp[r];                               \
      }                                                                        \
    }                                                                          \
    __syncthreads();                                                           \
    if (t < 32) {                                                              \
      float S = 0.f;                                                           \
      _Pragma("unroll") for (int w = 0; w < 8; ++w) S += red[w][t];            \
      row_s[t] = S + (CBV);                                                    \
    }                                                                          \
    __syncthreads();                                                           \
  }

// LN stats (sum -> red[wid], sumsq -> red[8+wid])
#define LN_STATS()                                                             \
  {                                                                            \
    _Pragma("unroll") for (int rt = 0; rt < 2; ++rt) {                         \
      float sA[4], sQ[4];                                                      \
      _Pragma("unroll") for (int r = 0; r < 4; ++r) {                          \
        float a0 = h[rt][0][r], a1 = h[rt][1][r];                              \
        sA[r] = a0 + a1;                                                       \
        sQ[r] = a0 * a0 + a1 * a1;                                             \
      }                                                                        \
      _Pragma("unroll") for (int r = 0; r < 4; ++r) {                          \
        sA[r] = sum16(sA[r]); sQ[r] = sum16(sQ[r]);                            \
      }                                                                        \
      if (li == 0) {                                                           \
        _Pragma("unroll") for (int r = 0; r < 4; ++r) {                        \
          int row_ = rt * 16 + g * 4 + r;                                      \
          red[wid][row_] = sA[r]; red[8 + wid][row_] = sQ[r];                  \
        }                                                                      \
      }                                                                        \
    }                                                                          \
    __syncthreads();                                                           \
    if (t < 32) {                                                              \
      float S = 0.f, Q = 0.f;                                                  \
      _Pragma("unroll") for (int w = 0; w < 8; ++w) { S += red[w][t]; Q += red[8 + w][t]; } \
      float mean_ = S * (1.f / 256.f);                                         \
      float var_ = Q * (1.f / 256.f) - mean_ * mean_;                          \
      mr_s[t][0] = mean_; mr_s[t][1] = rsqrtf(var_ + 1e-5f);                   \
    }                                                                          \
    __syncthreads();                                                           \
  }

__global__ __launch_bounds__(512) void fused_kernel(
    const float* __restrict__ x,
    const float* __restrict__ rp, const float* __restrict__ ub, const float* __restrict__ cbp,
    const unsigned short* __restrict__ Uws,
    const float* __restrict__ bin, const float* __restrict__ bo,
    const float* __restrict__ lng, const float* __restrict__ lnb,
    const float* __restrict__ bout, const float* __restrict__ lngf, const float* __restrict__ lnbf,
    float* __restrict__ out) {
  __shared__ unsigned short alds[8192];      // 16KB A fragments (32 rows x 256)
  __shared__ float c_bin[256], c_bout[256], c_lngf[256], c_lnbf[256];
  __shared__ float c_ub[2][256], c_bo[2][256], c_lng[2][256], c_lnb[2][256], c_rp[2][256];
  __shared__ float red[16][32];
  __shared__ float row_s[32], invz_s[32];
  __shared__ float mr_s[32][2];
  __shared__ float scal_s[4];                // Rm0, Rm1, cb0, cb1
  char* smc = (char*)alds;

  const int wg = blockIdx.x, t = threadIdx.x;
  const int wid = t >> 6, lane = t & 63, li = lane & 15, g = lane >> 4;
  const int rowbase = wg * 32;
  int ncol[2]; ncol[0] = wid * 32 + li; ncol[1] = wid * 32 + 16 + li;

  // R8: phase-desync stagger — co-resident WGs offset so their VALU / kloop /
  // barrier phases interleave instead of running in lockstep.
  {
    int ph = wg & 3;
    if (ph > 0) __builtin_amdgcn_s_sleep(24);
    if (ph > 1) __builtin_amdgcn_s_sleep(24);
    if (ph > 2) __builtin_amdgcn_s_sleep(24);
  }

  // constants -> LDS
  if (t < 256) {
    c_bin[t] = bin[t]; c_ub[0][t] = ub[t]; c_bo[0][t] = bo[t];
    c_lng[0][t] = lng[t]; c_lnb[0][t] = lnb[t]; c_rp[0][t] = rp[t];
  } else {
    int u = t - 256;
    c_bout[u] = bout[u]; c_lngf[u] = lngf[u]; c_lnbf[u] = lnbf[u];
    c_ub[1][u] = ub[256 + u]; c_bo[1][u] = bo[256 + u];
    c_lng[1][u] = lng[256 + u]; c_lnb[1][u] = lnb[256 + u]; c_rp[1][u] = rp[256 + u];
  }
  if (t == 0) { scal_s[2] = cbp[0]; scal_s[3] = cbp[1]; }

  // stage x -> alds (bf16, A-frag layout); NT ext-vector reads (x read exactly once —
  // don't let the 32MB stream evict the L2-resident B matrices)
#pragma unroll
  for (int it = 0; it < 4; ++it) {
    int flat = it * 2048 + t * 4;
    int m = flat >> 8, col = flat & 255;
    const f32x4 xv = __builtin_nontemporal_load((const f32x4*)(x + (rowbase + m) * 256 + col));
    ushort4 pk; pk.x = f2bf(xv.x); pk.y = f2bf(xv.y); pk.z = f2bf(xv.z); pk.w = f2bf(xv.w);
    *(ushort4*)(smc + alds_byte(col, m)) = pk;
  }
  __syncthreads();
  if (wid < 2) {   // Rm_l = max_f r'_l (once, 2 waves)
    float m2 = fmaxf(fmaxf(c_rp[wid][lane], c_rp[wid][lane + 64]),
                     fmaxf(c_rp[wid][lane + 128], c_rp[wid][lane + 192]));
#pragma unroll
    for (int mm = 1; mm < 64; mm <<= 1) m2 = fmaxf(m2, __shfl_xor(m2, mm, 64));
    if (lane == 0) scal_s[wid] = m2;
  }

  float h[2][2][4];

  // ---- stage 0: h0 = x@Win + bin ; s0 ----
  {
    f32x4 acc[2][2];
#pragma unroll
    for (int a = 0; a < 2; ++a)
#pragma unroll
      for (int c = 0; c < 2; ++c) { f32x4 z = {0.f, 0.f, 0.f, 0.f}; acc[a][c] = z; }
    kloop(smc, Uws, wid, lane, li, g, acc);
#pragma unroll
    for (int rt = 0; rt < 2; ++rt)
#pragma unroll
      for (int ct = 0; ct < 2; ++ct)
#pragma unroll
        for (int r = 0; r < 4; ++r) h[rt][ct][r] = acc[rt][ct][r] + c_bin[ncol[ct]];
    S_REDUCE(c_ub[0], scal_s[2]);
  }

  // ---- layers ----
#pragma unroll 1
  for (int l = 0; l < 2; ++l) {
    // alpha (un-normalized bf16) -> alds via b128 writes; Z partials
    {
      int row = t & 31, p = t >> 5;       // 16 threads per row, 16 features each
      float sm = row_s[row];
      float mx = lrelu(sm + scal_s[l]);   // exact max: lrelu monotone
      float z = 0.f;
#pragma unroll
      for (int j = 0; j < 2; ++j) {
        int grp = p * 2 + j;
        float w0 = __expf(lrelu(sm + c_rp[l][grp * 8 + 0]) - mx);
        float w1 = __expf(lrelu(sm + c_rp[l][grp * 8 + 1]) - mx);
        float w2 = __expf(lrelu(sm + c_rp[l][grp * 8 + 2]) - mx);
        float w3 = __expf(lrelu(sm + c_rp[l][grp * 8 + 3]) - mx);
        float w4 = __expf(lrelu(sm + c_rp[l][grp * 8 + 4]) - mx);
        float w5 = __expf(lrelu(sm + c_rp[l][grp * 8 + 5]) - mx);
        float w6 = __expf(lrelu(sm + c_rp[l][grp * 8 + 6]) - mx);
        float w7 = __expf(lrelu(sm + c_rp[l][grp * 8 + 7]) - mx);
        unsigned short u0 = f2bf(w0), u1 = f2bf(w1), u2 = f2bf(w2), u3 = f2bf(w3);
        unsigned short u4 = f2bf(w4), u5 = f2bf(w5), u6 = f2bf(w6), u7 = f2bf(w7);
        z += bf2f(u0) + bf2f(u1) + bf2f(u2) + bf2f(u3) +
             bf2f(u4) + bf2f(u5) + bf2f(u6) + bf2f(u7);
        uint4 pk;
        pk.x = (unsigned int)u0 | ((unsigned int)u1 << 16);
        pk.y = (unsigned int)u2 | ((unsigned int)u3 << 16);
        pk.z = (unsigned int)u4 | ((unsigned int)u5 << 16);
        pk.w = (unsigned int)u6 | ((unsigned int)u7 << 16);
        int byte = ((grp * 32 + row) * 16) ^ ((grp & 7) << 4);
        *(uint4*)(smc + byte) = pk;
      }
      red[p][row] = z;
    }
    __syncthreads();
    if (t < 32) {
      float Z = 0.f;
#pragma unroll
      for (int p = 0; p < 16; ++p) Z += red[p][t];
      invz_s[t] = 1.f / Z;
    }
    __syncthreads();

    f32x4 acc[2][2];
#pragma unroll
    for (int a = 0; a < 2; ++a)
#pragma unroll
      for (int c = 0; c < 2; ++c) { f32x4 z = {0.f, 0.f, 0.f, 0.f}; acc[a][c] = z; }
    kloop(smc, Uws + 131072 + l * 65536, wid, lane, li, g, acc);

    // h = LN(acc/Z + bo + h)
#pragma unroll
    for (int rt = 0; rt < 2; ++rt)
#pragma unroll
      for (int r = 0; r < 4; ++r) {
        int row = rt * 16 + g * 4 + r;
        float iz = invz_s[row];
#pragma unroll
        for (int ct = 0; ct < 2; ++ct)
          h[rt][ct][r] = fmaf(acc[rt][ct][r], iz, c_bo[l][ncol[ct]] + h[rt][ct][r]);
      }
    LN_STATS();
#pragma unroll
    for (int rt = 0; rt < 2; ++rt)
#pragma unroll
      for (int r = 0; r < 4; ++r) {
        int row = rt * 16 + g * 4 + r;
        float mean = mr_s[row][0], rstd = mr_s[row][1];
#pragma unroll
        for (int ct = 0; ct < 2; ++ct)
          h[rt][ct][r] = (h[rt][ct][r] - mean) * rstd * c_lng[l][ncol[ct]] + c_lnb[l][ncol[ct]];
      }
    if (l == 0) S_REDUCE(c_ub[1], scal_s[3]);
  }

  // ---- stage 3: out = LN(h@Wout + bout) ----
#pragma unroll
  for (int rt = 0; rt < 2; ++rt)
#pragma unroll
    for (int ct = 0; ct < 2; ++ct)
#pragma unroll
      for (int r = 0; r < 4; ++r) {
        int row = rt * 16 + g * 4 + r;
        *(unsigned short*)(smc + alds_byte(ncol[ct], row)) = f2bf(h[rt][ct][r]);
      }
  __syncthreads();
  {
    f32x4 acc[2][2];
#pragma unroll
    for (int a = 0; a < 2; ++a)
#pragma unroll
      for (int c = 0; c < 2; ++c) { f32x4 z = {0.f, 0.f, 0.f, 0.f}; acc[a][c] = z; }
    kloop(smc, Uws + 65536, wid, lane, li, g, acc);
#pragma unroll
    for (int rt = 0; rt < 2; ++rt)
#pragma unroll
      for (int ct = 0; ct < 2; ++ct)
#pragma unroll
        for (int r = 0; r < 4; ++r) h[rt][ct][r] = acc[rt][ct][r] + c_bout[ncol[ct]];
    LN_STATS();
#pragma unroll
    for (int rt = 0; rt < 2; ++rt)
#pragma unroll
      for (int r = 0; r < 4; ++r) {
        int row = rt * 16 + g * 4 + r;
        float mean = mr_s[row][0], rstd = mr_s[row][1];
#pragma unroll
        for (int ct = 0; ct < 2; ++ct) {
          float v = (h[rt][ct][r] - mean) * rstd * c_lngf[ncol[ct]] + c_lnbf[ncol[ct]];
          __builtin_nontemporal_store(v, out + (rowbase + row) * 256 + ncol[ct]);
        }
      }
  }
}

extern "C" void kernel_launch(void* const* d_in, const int* in_sizes, int n_in,
                              void* d_out, int out_size, void* d_ws, size_t ws_size,
                              hipStream_t stream) {
  const float* x    = (const float*)d_in[0];
  const int*   adj  = (const int*)d_in[1];
  const float* gdv  = (const float*)d_in[2];
  const float* Win  = (const float*)d_in[3];
  const float* bin  = (const float*)d_in[4];
  const float* Wout = (const float*)d_in[5];
  const float* bout = (const float*)d_in[6];
  const float* g1W  = (const float*)d_in[7];
  const float* g1b  = (const float*)d_in[8];
  const float* g2W  = (const float*)d_in[9];
  const float* g2b  = (const float*)d_in[10];
  const float* grW  = (const float*)d_in[11];
  const float* grb  = (const float*)d_in[12];
  const float* lngf = (const float*)d_in[13];
  const float* lnbf = (const float*)d_in[14];
  const float* Wf   = (const float*)d_in[15];
  const float* bfv  = (const float*)d_in[16];
  const float* Wt   = (const float*)d_in[17];
  const float* bt   = (const float*)d_in[18];
  const float* waf  = (const float*)d_in[19];
  const float* baf  = (const float*)d_in[20];
  const float* wat  = (const float*)d_in[21];
  const float* bat  = (const float*)d_in[22];
  const float* Wo   = (const float*)d_in[23];
  const float* bo   = (const float*)d_in[24];
  const float* lng  = (const float*)d_in[25];
  const float* lnb  = (const float*)d_in[26];
  float* out = (float*)d_out;

  float* W = (float*)d_ws;
  float* Tp = W;                                 // 2*256*256
  float* pb = W + 131072;                        // 512
  float* qb = W + 131584;
  float* rp = W + 132096;
  float* ub = W + 132608;
  float* cb = W + 133120;                        // 2 (+pad)
  unsigned short* Uws = (unsigned short*)(W + 133184);  // Win|Wout|M0|M1 swz bf16 (512KB)

  ta_kernel<<<512, 256, 0, stream>>>(gdv, g1W, g1b, g2W, g2b, grW, grb, Wt, bt, wat, Tp, pb, qb);
  tb_kernel<<<544, 256, 0, stream>>>(adj, Tp, pb, qb, bat, Wo, waf, baf, Wf, bfv, Win, Wout, rp, ub, cb, Uws);
  fused_kernel<<<1024, 512, 0, stream>>>(x, rp, ub, cb, Uws, bin, bo, lng, lnb, bout, lngf, lnbf, out);
}

// Round 10
// 68.024 us; speedup vs baseline: 1.1092x; 1.0227x over previous
//
#include <hip/hip_runtime.h>
#include <hip/hip_bf16.h>

// GTAT integrated: B=8,N=4096,D=256,TD=64,GD=73,L=2 -> 32768 rows, row-parallel.
// TA (t,Tp,p,q) -> TB (beta,T_out,M=T_out@Wo swz, r',u,c, W swizzles)
//  -> fused (all 4 GEMM stages, h in registers, 32 rows/WG x 1024 WGs)
// R10: (a) stagger fixed to (wg>>8)&3 — co-resident WGs (stride 256) now truly
//      phase-offset; (b) v_cvt_pk_bf16_f32 for all f32->bf16 pairs (~30% VALU cut);
//      (c) layer-0 s-reduction algebraically fused into LN stats (one pass, -2 barriers).

typedef float f32x4 __attribute__((ext_vector_type(4)));
typedef short bf16x8 __attribute__((ext_vector_type(8)));

__device__ __forceinline__ unsigned int cvt_pk(float lo, float hi) {
  unsigned int r;
  asm("v_cvt_pk_bf16_f32 %0, %1, %2" : "=v"(r) : "v"(lo), "v"(hi));
  return r;   // lo16 = bf16(lo), hi16 = bf16(hi)
}
__device__ __forceinline__ float bfl(unsigned int p) {        // f32 of low bf16
  return __builtin_bit_cast(float, p << 16);
}
__device__ __forceinline__ float bfh(unsigned int p) {        // f32 of high bf16
  return __builtin_bit_cast(float, p & 0xFFFF0000u);
}
__device__ __forceinline__ unsigned short f2bf(float f) {
  unsigned int u = __builtin_bit_cast(unsigned int, f);
  u += 0x7FFFu + ((u >> 16) & 1u);
  return (unsigned short)(u >> 16);
}
__device__ __forceinline__ float lrelu(float x) { return x > 0.f ? x : 0.01f * x; }

// ---- DPP 16-lane reduction (VALU only, no LDS pipe) ----
template <int CTRL>
__device__ __forceinline__ float dpp_ror_add(float v) {
  int s = __builtin_amdgcn_update_dpp(0, __builtin_bit_cast(int, v), CTRL, 0xf, 0xf, true);
  return v + __builtin_bit_cast(float, s);
}
__device__ __forceinline__ float sum16(float v) {
  v = dpp_ror_add<0x128>(v);
  v = dpp_ror_add<0x124>(v);
  v = dpp_ror_add<0x122>(v);
  v = dpp_ror_add<0x121>(v);
  return v;
}

// ---- block reduce helpers (256 threads, all must call) ----
__device__ __forceinline__ float block_sum(float v, float* s4, int t) {
  v = sum16(v);
  v += __shfl_xor(v, 16, 64);
  v += __shfl_xor(v, 32, 64);
  __syncthreads();
  if ((t & 63) == 0) s4[t >> 6] = v;
  __syncthreads();
  return s4[0] + s4[1] + s4[2] + s4[3];
}
__device__ __forceinline__ float block_max(float v, float* s4, int t) {
#pragma unroll
  for (int m = 1; m < 64; m <<= 1) v = fmaxf(v, __shfl_xor(v, m, 64));
  __syncthreads();
  if ((t & 63) == 0) s4[t >> 6] = v;
  __syncthreads();
  return fmaxf(fmaxf(s4[0], s4[1]), fmaxf(s4[2], s4[3]));
}

// B-operand swizzled layout
__device__ __forceinline__ int swz_off(int k, int n) {
  return ((((k >> 5) * 16 + (n >> 4)) * 4 + ((k >> 3) & 3)) * 16 + (n & 15)) * 8 + (k & 7);
}
// A-frag LDS byte offset for (k=n, row m in [0,32)), XOR-swizzled
__device__ __forceinline__ int alds_byte(int n, int m) {
  int grp = n >> 3;
  int base = (grp * 32 + m) * 16 + (n & 7) * 2;
  return base ^ ((grp & 7) << 4);
}

// ============ TA: t rows -> Tp rows + p,q  (grid 512 = L*256, 256 thr) ============
__global__ void ta_kernel(const float* __restrict__ gdv,
                          const float* __restrict__ g1W, const float* __restrict__ g1b,
                          const float* __restrict__ g2W, const float* __restrict__ g2b,
                          const float* __restrict__ grW, const float* __restrict__ grb,
                          const float* __restrict__ Wt, const float* __restrict__ bt,
                          const float* __restrict__ wat,
                          float* __restrict__ Tp, float* __restrict__ pb, float* __restrict__ qb) {
  int l = blockIdx.x >> 8, i = blockIdx.x & 255, t = threadIdx.x;
  __shared__ float gs[73], as_[64], ts[64], s4[4];
  float gv = (t < 73) ? gdv[i * 73 + t] : 0.f;
  float gsum = block_sum(gv, s4, t);
  if (t < 73) gs[t] = gv / (gsum + 1e-6f);
  __syncthreads();
  if (t < 64) {
    float a = g1b[t], gr = grb[t];
    for (int k = 0; k < 73; ++k) { float gk = gs[k]; a = fmaf(gk, g1W[k * 64 + t], a); gr = fmaf(gk, grW[k * 64 + t], gr); }
    as_[t] = fmaxf(a, 0.f);
    ts[t] = gr + g2b[t];
  }
  __syncthreads();
  float tv = 0.f;
  if (t < 64) {
    tv = ts[t];
    for (int k = 0; k < 64; ++k) tv = fmaf(as_[k], g2W[k * 64 + t], tv);
  }
  __syncthreads();
  if (t < 64) ts[t] = tv;
  __syncthreads();
  float tp = bt[l * 256 + t];
  for (int k = 0; k < 64; ++k) tp = fmaf(ts[k], Wt[(l * 64 + k) * 256 + t], tp);
  Tp[(l * 256 + i) * 256 + t] = tp;
  float pp = block_sum(tp * wat[l * 512 + t], s4, t);
  float qq = block_sum(tp * wat[l * 512 + 256 + t], s4, t);
  if (t == 0) { pb[l * 256 + i] = pp; qb[l * 256 + i] = qq; }
}

// ====== TB: beta,T_out row -> M row (swz bf16), r', u, c ; + W_in/W_out swizzles ======
__global__ void tb_kernel(const int* __restrict__ adj, const float* __restrict__ Tp,
                          const float* __restrict__ pb, const float* __restrict__ qb,
                          const float* __restrict__ batopo, const float* __restrict__ Wo,
                          const float* __restrict__ wafeat, const float* __restrict__ bafeat,
                          const float* __restrict__ Wf, const float* __restrict__ bfv,
                          const float* __restrict__ Win, const float* __restrict__ Wout,
                          float* __restrict__ rp, float* __restrict__ ub, float* __restrict__ cb,
                          unsigned short* __restrict__ Uws) {
  int b = blockIdx.x, t = threadIdx.x;
  if (b >= 512) {
    int bb = b - 512;
    const float* src = (bb < 16) ? Win : Wout;
    unsigned short* dst = Uws + ((bb < 16) ? 0 : 65536);
    int r0 = (bb & 15) * 16;
    for (int kk = 0; kk < 16; ++kk) {
      int k = r0 + kk;
      dst[swz_off(k, t)] = f2bf(src[k * 256 + t]);
    }
    return;
  }
  int l = b >> 8, i = b & 255;
  __shared__ float beta[256], tout[256], s4[4];
  float e = pb[l * 256 + i] + qb[l * 256 + t] + batopo[l];
  e = lrelu(e);
  if (adj[i * 256 + t] == 0) e = -1e9f;
  float mx = block_max(e, s4, t);
  float w = __expf(e - mx);
  float Z = block_sum(w, s4, t);
  beta[t] = w / Z;
  __syncthreads();
  float acc = 0.f;
  for (int j = 0; j < 256; ++j) acc = fmaf(beta[j], Tp[(l * 256 + j) * 256 + t], acc);
  tout[t] = acc;
  __syncthreads();
  const float* WoL = Wo + l * 65536;
  float macc = 0.f;
  for (int h2 = 0; h2 < 256; ++h2) macc = fmaf(tout[h2], WoL[h2 * 256 + t], macc);
  Uws[131072 + l * 65536 + swz_off(i, t)] = f2bf(macc);
  const float* wf = wafeat + l * 512;
  float rsum = block_sum(tout[t] * wf[256 + t], s4, t);
  if (t == 0) rp[l * 256 + i] = rsum + bafeat[l];
  float usum = block_sum(Wf[(l * 256 + i) * 256 + t] * wf[t], s4, t);
  if (t == 0) ub[l * 256 + i] = usum;
  if (i == 0) {
    float csum = block_sum(bfv[l * 256 + t] * wf[t], s4, t);
    if (t == 0) cb[l] = csum;
  }
}

// ============ fused kernel: 4 GEMM stages, 1024 WGs x 512 thr, 32 rows/WG ============
#define MFMA(A, B, C) __builtin_amdgcn_mfma_f32_16x16x32_bf16(A, B, C, 0, 0, 0)

__device__ __forceinline__ void kloop(const char* smc, const unsigned short* Bws,
                                      int wid, int lane, int li, int g, f32x4 acc[2][2]) {
  const bf16x8* Bw = (const bf16x8*)Bws + wid * 2 * 64 + lane;
  bf16x8 b0a = Bw[0], b1a = Bw[64];
  bf16x8 b0b = Bw[1024], b1b = Bw[1024 + 64];
#pragma unroll
  for (int kb = 0; kb < 8; ++kb) {
    bf16x8 nb0, nb1;
    if (kb < 6) {
      nb0 = Bw[(kb + 2) * 1024];
      nb1 = Bw[(kb + 2) * 1024 + 64];
    }
    int grp = kb * 4 + g;
    int ab = ((grp * 32 + li) * 16) ^ ((grp & 7) << 4);
    bf16x8 a0 = *(const bf16x8*)(smc + ab);
    bf16x8 a1 = *(const bf16x8*)(smc + ab + 256);
    __builtin_amdgcn_s_setprio(1);
    acc[0][0] = MFMA(a0, b0a, acc[0][0]);
    acc[1][0] = MFMA(a1, b0a, acc[1][0]);
    acc[0][1] = MFMA(a0, b1a, acc[0][1]);
    acc[1][1] = MFMA(a1, b1a, acc[1][1]);
    __builtin_amdgcn_s_setprio(0);
    b0a = b0b; b1a = b1b;
    if (kb < 6) { b0b = nb0; b1b = nb1; }
  }
}

// s = h . u + c per row (rows 0..31)
#define S_REDUCE(UBARR, CBV)                                                   \
  {                                                                            \
    float u0_ = UBARR[ncol[0]], u1_ = UBARR[ncol[1]];                          \
    _Pragma("unroll") for (int rt = 0; rt < 2; ++rt) {                         \
      float sp[4];                                                             \
      _Pragma("unroll") for (int r = 0; r < 4; ++r)                            \
        sp[r] = h[rt][0][r] * u0_ + h[rt][1][r] * u1_;                         \
      _Pragma("unroll") for (int r = 0; r < 4; ++r) sp[r] = sum16(sp[r]);      \
      if (li == 0) {                                                           \
        _Pragma("unroll") for (int r = 0; r < 4; ++r)                          \
          red[wid][rt * 16 + g * 4 + r] = sp[r];                               \
      }                                                                        \
    }                                                                          \
    __syncthreads();                                                           \
    if (t < 32) {                                                              \
      float S = 0.f;                                                           \
      _Pragma("unroll") for (int w = 0; w < 8; ++w) S += red[w][t];            \
      row_s[t] = S + (CBV);                                                    \
    }                                                                          \
    __syncthreads();                                                           \
  }

// LN stats, 2-sum (layers with no s needed)
#define LN_STATS()                                                             \
  {                                                                            \
    _Pragma("unroll") for (int rt = 0; rt < 2; ++rt) {                         \
      float sA[4], sQ[4];                                                      \
      _Pragma("unroll") for (int r = 0; r < 4; ++r) {                          \
        float a0 = h[rt][0][r], a1 = h[rt][1][r];                              \
        sA[r] = a0 + a1;                                                       \
        sQ[r] = a0 * a0 + a1 * a1;                                             \
      }                                                                        \
      _Pragma("unroll") for (int r = 0; r < 4; ++r) {                          \
        sA[r] = sum16(sA[r]); sQ[r] = sum16(sQ[r]);                            \
      }                                                                        \
      if (li == 0) {                                                           \
        _Pragma("unroll") for (int r = 0; r < 4; ++r) {                        \
          int row_ = rt * 16 + g * 4 + r;                                      \
          red[wid][row_] = sA[r]; red[8 + wid][row_] = sQ[r];                  \
        }                                                                      \
      }                                                                        \
    }                                                                          \
    __syncthreads();                                                           \
    if (t < 32) {                                                              \
      float S = 0.f, Q = 0.f;                                                  \
      _Pragma("unroll") for (int w = 0; w < 8; ++w) { S += red[w][t]; Q += red[8 + w][t]; } \
      float mean_ = S * (1.f / 256.f);                                         \
      float var_ = Q * (1.f / 256.f) - mean_ * mean_;                          \
      mr_s[t][0] = mean_; mr_s[t][1] = rsqrtf(var_ + 1e-5f);                   \
    }                                                                          \
    __syncthreads();                                                           \
  }

// LN stats 3-sum (layer 0): also computes s = rstd*(G - mean*GU) + BU in one pass
// (s = sum_f h_norm[f]*u1[f] + cb1, algebraically expanded; GU/BU in scal_s[4/5])
#define LN_STATS3()                                                            \
  {                                                                            \
    float gu0 = c_gu[ncol[0]], gu1 = c_gu[ncol[1]];                            \
    _Pragma("unroll") for (int rt = 0; rt < 2; ++rt) {                         \
      float sA[4], sQ[4], sG[4];                                               \
      _Pragma("unroll") for (int r = 0; r < 4; ++r) {                          \
        float a0 = h[rt][0][r], a1 = h[rt][1][r];                              \
        sA[r] = a0 + a1;                                                       \
        sQ[r] = a0 * a0 + a1 * a1;                                             \
        sG[r] = a0 * gu0 + a1 * gu1;                                           \
      }                                                                        \
      _Pragma("unroll") for (int r = 0; r < 4; ++r) {                          \
        sA[r] = sum16(sA[r]); sQ[r] = sum16(sQ[r]); sG[r] = sum16(sG[r]);      \
      }                                                                        \
      if (li == 0) {                                                           \
        _Pragma("unroll") for (int r = 0; r < 4; ++r) {                        \
          int row_ = rt * 16 + g * 4 + r;                                      \
          red[wid][row_] = sA[r]; red[8 + wid][row_] = sQ[r];                  \
          red[16 + wid][row_] = sG[r];                                         \
        }                                                                      \
      }                                                                        \
    }                                                                          \
    __syncthreads();                                                           \
    if (t < 32) {                                                              \
      float S = 0.f, Q = 0.f, G = 0.f;                                         \
      _Pragma("unroll") for (int w = 0; w < 8; ++w) {                          \
        S += red[w][t]; Q += red[8 + w][t]; G += red[16 + w][t];               \
      }                                                                        \
      float mean_ = S * (1.f / 256.f);                                         \
      float var_ = Q * (1.f / 256.f) - mean_ * mean_;                          \
      float rstd_ = rsqrtf(var_ + 1e-5f);                                      \
      mr_s[t][0] = mean_; mr_s[t][1] = rstd_;                                  \
      row_s[t] = rstd_ * (G - mean_ * scal_s[4]) + scal_s[5];                  \
    }                                                                          \
    __syncthreads();                                                           \
  }

__global__ __launch_bounds__(512) void fused_kernel(
    const float* __restrict__ x,
    const float* __restrict__ rp, const float* __restrict__ ub, const float* __restrict__ cbp,
    const unsigned short* __restrict__ Uws,
    const float* __restrict__ bin, const float* __restrict__ bo,
    const float* __restrict__ lng, const float* __restrict__ lnb,
    const float* __restrict__ bout, const float* __restrict__ lngf, const float* __restrict__ lnbf,
    float* __restrict__ out) {
  __shared__ unsigned short alds[8192];      // 16KB A fragments (32 rows x 256)
  __shared__ float c_bin[256], c_bout[256], c_lngf[256], c_lnbf[256];
  __shared__ float c_ub[2][256], c_bo[2][256], c_lng[2][256], c_lnb[2][256], c_rp[2][256];
  __shared__ float c_gu[256];                // lng0 ⊙ u1
  __shared__ float red[24][32];
  __shared__ float row_s[32], invz_s[32];
  __shared__ float mr_s[32][2];
  __shared__ float scal_s[8];                // Rm0, Rm1, cb0, cb1, GU, BU
  char* smc = (char*)alds;

  const int wg = blockIdx.x, t = threadIdx.x;
  const int wid = t >> 6, lane = t & 63, li = lane & 15, g = lane >> 4;
  const int rowbase = wg * 32;
  int ncol[2]; ncol[0] = wid * 32 + li; ncol[1] = wid * 32 + 16 + li;

  // R10: co-resident WGs are {i, i+256, i+512, i+768} -> phase by (wg>>8)&3.
  {
    int ph = (wg >> 8) & 3;
    if (ph > 0) __builtin_amdgcn_s_sleep(39);   // ~2500 cyc per step
    if (ph > 1) __builtin_amdgcn_s_sleep(39);
    if (ph > 2) __builtin_amdgcn_s_sleep(39);
  }

  // constants -> LDS
  if (t < 256) {
    c_bin[t] = bin[t]; c_ub[0][t] = ub[t]; c_bo[0][t] = bo[t];
    c_lng[0][t] = lng[t]; c_lnb[0][t] = lnb[t]; c_rp[0][t] = rp[t];
  } else {
    int u = t - 256;
    c_bout[u] = bout[u]; c_lngf[u] = lngf[u]; c_lnbf[u] = lnbf[u];
    c_ub[1][u] = ub[256 + u]; c_bo[1][u] = bo[256 + u];
    c_lng[1][u] = lng[256 + u]; c_lnb[1][u] = lnb[256 + u]; c_rp[1][u] = rp[256 + u];
  }
  if (t == 0) { scal_s[2] = cbp[0]; scal_s[3] = cbp[1]; }

  // stage x -> alds (bf16, A-frag layout); NT reads, cvt_pk conversion
#pragma unroll
  for (int it = 0; it < 4; ++it) {
    int flat = it * 2048 + t * 4;
    int m = flat >> 8, col = flat & 255;
    const f32x4 xv = __builtin_nontemporal_load((const f32x4*)(x + (rowbase + m) * 256 + col));
    uint2 pk; pk.x = cvt_pk(xv.x, xv.y); pk.y = cvt_pk(xv.z, xv.w);
    *(uint2*)(smc + alds_byte(col, m)) = pk;
  }
  __syncthreads();
  if (wid < 2) {   // Rm_l = max_f r'_l
    float m2 = fmaxf(fmaxf(c_rp[wid][lane], c_rp[wid][lane + 64]),
                     fmaxf(c_rp[wid][lane + 128], c_rp[wid][lane + 192]));
#pragma unroll
    for (int mm = 1; mm < 64; mm <<= 1) m2 = fmaxf(m2, __shfl_xor(m2, mm, 64));
    if (lane == 0) scal_s[wid] = m2;
  } else if (wid == 2) {  // GU = sum lng0*u1 ; BU = sum lnb0*u1 + cb1 ; fill c_gu
    float ga = 0.f, ba = 0.f;
#pragma unroll
    for (int j = 0; j < 4; ++j) {
      int idx = lane * 4 + j;
      float u1v = c_ub[1][idx];
      float gv = c_lng[0][idx] * u1v;
      c_gu[idx] = gv;
      ga += gv;
      ba = fmaf(c_lnb[0][idx], u1v, ba);
    }
    ga = sum16(ga); ga += __shfl_xor(ga, 16, 64); ga += __shfl_xor(ga, 32, 64);
    ba = sum16(ba); ba += __shfl_xor(ba, 16, 64); ba += __shfl_xor(ba, 32, 64);
    if (lane == 0) { scal_s[4] = ga; scal_s[5] = ba + scal_s[3]; }
  }

  float h[2][2][4];

  // ---- stage 0: h0 = x@Win + bin ; s0 ----
  {
    f32x4 acc[2][2];
#pragma unroll
    for (int a = 0; a < 2; ++a)
#pragma unroll
      for (int c = 0; c < 2; ++c) { f32x4 z = {0.f, 0.f, 0.f, 0.f}; acc[a][c] = z; }
    kloop(smc, Uws, wid, lane, li, g, acc);
#pragma unroll
    for (int rt = 0; rt < 2; ++rt)
#pragma unroll
      for (int ct = 0; ct < 2; ++ct)
#pragma unroll
        for (int r = 0; r < 4; ++r) h[rt][ct][r] = acc[rt][ct][r] + c_bin[ncol[ct]];
    S_REDUCE(c_ub[0], scal_s[2]);
  }

  // ---- layers ----
#pragma unroll 1
  for (int l = 0; l < 2; ++l) {
    // alpha (un-normalized bf16) -> alds via b128 writes; Z partials
    {
      int row = t & 31, p = t >> 5;       // 16 threads per row, 16 features each
      float sm = row_s[row];
      float mx = lrelu(sm + scal_s[l]);   // exact max: lrelu monotone
      float z = 0.f;
#pragma unroll
      for (int j = 0; j < 2; ++j) {
        int grp = p * 2 + j;
        f32x4 ra = *(const f32x4*)&c_rp[l][grp * 8];
        f32x4 rb = *(const f32x4*)&c_rp[l][grp * 8 + 4];
        float w0 = __expf(lrelu(sm + ra.x) - mx);
        float w1 = __expf(lrelu(sm + ra.y) - mx);
        float w2 = __expf(lrelu(sm + ra.z) - mx);
        float w3 = __expf(lrelu(sm + ra.w) - mx);
        float w4 = __expf(lrelu(sm + rb.x) - mx);
        float w5 = __expf(lrelu(sm + rb.y) - mx);
        float w6 = __expf(lrelu(sm + rb.z) - mx);
        float w7 = __expf(lrelu(sm + rb.w) - mx);
        uint4 pk;
        pk.x = cvt_pk(w0, w1); pk.y = cvt_pk(w2, w3);
        pk.z = cvt_pk(w4, w5); pk.w = cvt_pk(w6, w7);
        z += bfl(pk.x) + bfh(pk.x) + bfl(pk.y) + bfh(pk.y) +
             bfl(pk.z) + bfh(pk.z) + bfl(pk.w) + bfh(pk.w);
        int byte = ((grp * 32 + row) * 16) ^ ((grp & 7) << 4);
        *(uint4*)(smc + byte) = pk;
      }
      red[p][row] = z;
    }
    __syncthreads();
    if (t < 32) {
      float Z = 0.f;
#pragma unroll
      for (int p = 0; p < 16; ++p) Z += red[p][t];
      invz_s[t] = 1.f / Z;
    }
    __syncthreads();

    f32x4 acc[2][2];
#pragma unroll
    for (int a = 0; a < 2; ++a)
#pragma unroll
      for (int c = 0; c < 2; ++c) { f32x4 z = {0.f, 0.f, 0.f, 0.f}; acc[a][c] = z; }
    kloop(smc, Uws + 131072 + l * 65536, wid, lane, li, g, acc);

    // h = LN(acc/Z + bo + h)
#pragma unroll
    for (int rt = 0; rt < 2; ++rt)
#pragma unroll
      for (int r = 0; r < 4; ++r) {
        int row = rt * 16 + g * 4 + r;
        float iz = invz_s[row];
#pragma unroll
        for (int ct = 0; ct < 2; ++ct)
          h[rt][ct][r] = fmaf(acc[rt][ct][r], iz, c_bo[l][ncol[ct]] + h[rt][ct][r]);
      }
    if (l == 0) { LN_STATS3(); } else { LN_STATS(); }
#pragma unroll
    for (int rt = 0; rt < 2; ++rt)
#pragma unroll
      for (int r = 0; r < 4; ++r) {
        int row = rt * 16 + g * 4 + r;
        float mean = mr_s[row][0], rstd = mr_s[row][1];
#pragma unroll
        for (int ct = 0; ct < 2; ++ct)
          h[rt][ct][r] = (h[rt][ct][r] - mean) * rstd * c_lng[l][ncol[ct]] + c_lnb[l][ncol[ct]];
      }
  }

  // ---- stage 3: out = LN(h@Wout + bout) ----
#pragma unroll
  for (int rt = 0; rt < 2; ++rt)
#pragma unroll
    for (int r = 0; r < 4; ++r) {
      int row = rt * 16 + g * 4 + r;
      unsigned int p = cvt_pk(h[rt][0][r], h[rt][1][r]);
      *(unsigned short*)(smc + alds_byte(ncol[0], row)) = (unsigned short)p;
      *(unsigned short*)(smc + alds_byte(ncol[1], row)) = (unsigned short)(p >> 16);
    }
  __syncthreads();
  {
    f32x4 acc[2][2];
#pragma unroll
    for (int a = 0; a < 2; ++a)
#pragma unroll
      for (int c = 0; c < 2; ++c) { f32x4 z = {0.f, 0.f, 0.f, 0.f}; acc[a][c] = z; }
    kloop(smc, Uws + 65536, wid, lane, li, g, acc);
#pragma unroll
    for (int rt = 0; rt < 2; ++rt)
#pragma unroll
      for (int ct = 0; ct < 2; ++ct)
#pragma unroll
        for (int r = 0; r < 4; ++r) h[rt][ct][r] = acc[rt][ct][r] + c_bout[ncol[ct]];
    LN_STATS();
#pragma unroll
    for (int rt = 0; rt < 2; ++rt)
#pragma unroll
      for (int r = 0; r < 4; ++r) {
        int row = rt * 16 + g * 4 + r;
        float mean = mr_s[row][0], rstd = mr_s[row][1];
#pragma unroll
        for (int ct = 0; ct < 2; ++ct) {
          float v = (h[rt][ct][r] - mean) * rstd * c_lngf[ncol[ct]] + c_lnbf[ncol[ct]];
          __builtin_nontemporal_store(v, out + (rowbase + row) * 256 + ncol[ct]);
        }
      }
  }
}

extern "C" void kernel_launch(void* const* d_in, const int* in_sizes, int n_in,
                              void* d_out, int out_size, void* d_ws, size_t ws_size,
                              hipStream_t stream) {
  const float* x    = (const float*)d_in[0];
  const int*   adj  = (const int*)d_in[1];
  const float* gdv  = (const float*)d_in[2];
  const float* Win  = (const float*)d_in[3];
  const float* bin  = (const float*)d_in[4];
  const float* Wout = (const float*)d_in[5];
  const float* bout = (const float*)d_in[6];
  const float* g1W  = (const float*)d_in[7];
  const float* g1b  = (const float*)d_in[8];
  const float* g2W  = (const float*)d_in[9];
  const float* g2b  = (const float*)d_in[10];
  const float* grW  = (const float*)d_in[11];
  const float* grb  = (const float*)d_in[12];
  const float* lngf = (const float*)d_in[13];
  const float* lnbf = (const float*)d_in[14];
  const float* Wf   = (const float*)d_in[15];
  const float* bfv  = (const float*)d_in[16];
  const float* Wt   = (const float*)d_in[17];
  const float* bt   = (const float*)d_in[18];
  const float* waf  = (const float*)d_in[19];
  const float* baf  = (const float*)d_in[20];
  const float* wat  = (const float*)d_in[21];
  const float* bat  = (const float*)d_in[22];
  const float* Wo   = (const float*)d_in[23];
  const float* bo   = (const float*)d_in[24];
  const float* lng  = (const float*)d_in[25];
  const float* lnb  = (const float*)d_in[26];
  float* out = (float*)d_out;

  float* W = (float*)d_ws;
  float* Tp = W;                                 // 2*256*256
  float* pb = W + 131072;                        // 512
  float* qb = W + 131584;
  float* rp = W + 132096;
  float* ub = W + 132608;
  float* cb = W + 133120;                        // 2 (+pad)
  unsigned short* Uws = (unsigned short*)(W + 133184);  // Win|Wout|M0|M1 swz bf16 (512KB)

  ta_kernel<<<512, 256, 0, stream>>>(gdv, g1W, g1b, g2W, g2b, grW, grb, Wt, bt, wat, Tp, pb, qb);
  tb_kernel<<<544, 256, 0, stream>>>(adj, Tp, pb, qb, bat, Wo, waf, baf, Wf, bfv, Win, Wout, rp, ub, cb, Uws);
  fused_kernel<<<1024, 512, 0, stream>>>(x, rp, ub, cb, Uws, bin, bo, lng, lnb, bout, lngf, lnbf, out);
}